// Round 2
// baseline (625.803 us; speedup 1.0000x reference)
//
#include <hip/hip_runtime.h>
#include <stdint.h>

typedef short short8 __attribute__((ext_vector_type(8)));
typedef float f32x16 __attribute__((ext_vector_type(16)));
typedef unsigned int uint;

#define NREG 49
#define NQ   100
#define CC   256
#define LSTR 72                    // LDS row stride in bf16 elems (64 + 8 pad, 144 B)
#define OUT_POS_OFF 5017600        // 4*49*100*256
#define PO_PER (NQ*CC)             // 25600 floats per (bn,seg) partial
#define QF_BYTES 131072
#define MFMA_BF16 __builtin_amdgcn_mfma_f32_32x32x16_bf16

__device__ __forceinline__ uint16_t f2bf_rne(float x){
    uint u = __float_as_uint(x);
    u += 0x7fffu + ((u >> 16) & 1u);
    return (uint16_t)(u >> 16);
}
__device__ __forceinline__ float bf2f(uint16_t b){
    return __uint_as_float(((uint)b) << 16);
}

// ---------------------------------------------------------------------------
// Kernel 0: precompute Q fragments (bf16 hi/lo) in exact 32x32x16 B-operand
// order: frag = qt*16 + k ; per lane 16B hi + 16B lo.
// ---------------------------------------------------------------------------
__global__ __launch_bounds__(512) void qfrag_kernel(const float* __restrict__ Qg,
                                                    uint4* __restrict__ qf){
    int gid  = blockIdx.x * 512 + threadIdx.x;   // 0..4095
    int lane = gid & 63;
    int frag = gid >> 6;                         // 0..63
    int k    = frag & 15;
    int qt   = frag >> 4;
    int q    = qt * 32 + (lane & 31);
    int c0   = k * 16 + (lane >> 5) * 8;
    float v[8];
#pragma unroll
    for (int j = 0; j < 8; ++j) v[j] = (q < NQ) ? Qg[q * CC + c0 + j] : 0.f;
    uint hu[4], lu[4];
#pragma unroll
    for (int j = 0; j < 4; ++j){
        uint16_t h0 = f2bf_rne(v[2*j]), h1 = f2bf_rne(v[2*j+1]);
        uint16_t l0 = f2bf_rne(v[2*j]   - bf2f(h0));
        uint16_t l1 = f2bf_rne(v[2*j+1] - bf2f(h1));
        hu[j] = (uint)h0 | ((uint)h1 << 16);
        lu[j] = (uint)l0 | ((uint)l1 << 16);
    }
    qf[(size_t)gid * 2]     = make_uint4(hu[0], hu[1], hu[2], hu[3]);
    qf[(size_t)gid * 2 + 1] = make_uint4(lu[0], lu[1], lu[2], lu[3]);
}

// ---------------------------------------------------------------------------
// Phase A: fused attention over a contiguous s-segment of one (b, region).
// grid = 196*split, 512 threads. split==1 writes normalized out directly;
// split>1 writes unnormalized O + l partials to workspace.
// ---------------------------------------------------------------------------
__global__ __launch_bounds__(512, 4) void attn_kernel(
        const float* __restrict__ img, const float* __restrict__ Qg,
        const uint4* __restrict__ qf, float* __restrict__ out,
        float* __restrict__ po, float* __restrict__ pl, int split)
{
    __shared__ uint16_t sRT[256 * LSTR];   // r chunk, bf16, transposed [c][s]  36864 B
    __shared__ uint16_t sP [128 * LSTR];   // P chunk, bf16, [q][s]             18432 B
    __shared__ float    sL [128];          // softmax partial denominators

    const int tid = threadIdx.x;
    const int seg = blockIdx.x % split;
    const int bn  = blockIdx.x / split;    // 0..195
    const int rr  = bn % NREG;
    const int bb  = bn / NREG;
    const int gh  = rr / 7, gw = rr % 7;

    if (bn == 0 && seg == 0 && tid < NREG){    // positions output
        out[OUT_POS_OFF + 2 * tid]     = (float)((tid / 7) / 7.0);
        out[OUT_POS_OFF + 2 * tid + 1] = (float)((tid % 7) / 7.0);
    }
    if (tid < 128) sL[tid] = 0.f;

    const int lane = tid & 63, w = tid >> 6;
    const int l31  = lane & 31, lh = lane >> 5;
    const int st = w & 1, qt = w >> 1;     // GEMM1 roles: s-tile, q-tile
    const int mp = w & 1, cq = w >> 1;     // GEMM2 roles: q-half, c-quarter

    const float* rbase = img + ((size_t)(bb * 224 + gh * 32) * 224 + gw * 32) * CC;

    f32x16 acc00, acc01, acc10, acc11;
#pragma unroll
    for (int i = 0; i < 16; ++i){ acc00[i]=0.f; acc01[i]=0.f; acc10[i]=0.f; acc11[i]=0.f; }
    float lp = 0.f;
    const int qq = qt * 32 + l31;

    union V8 { uint u[4]; short8 v; };

    const int nch = 16 / split;
    const int ch0 = seg * nch, ch1 = ch0 + nch;

    for (int ch = ch0; ch < ch1; ++ch){
        const int s0 = ch * 64;

        // ---- GEMM1: scores^T[s][q] = r · q (3-pass bf16 split),
        //      with inline transpose of rh into sRT by waves qt<2 ----
        f32x16 a1a, a1b;
#pragma unroll
        for (int i = 0; i < 16; ++i){ a1a[i] = 0.f; a1b[i] = 0.f; }
        {
            // wave's s-tile is one pixel row: hr = s0/32 + st, wr = l31
            const float* ar = rbase + (((s0 >> 5) + st) * 224 + l31) * CC;
            if (qf != nullptr){
#pragma unroll
                for (int k = 0; k < 16; ++k){
                    int c0 = k * 16 + lh * 8;
                    float4 v0 = *(const float4*)(ar + c0);
                    float4 v1 = *(const float4*)(ar + c0 + 4);
                    float vv[8] = {v0.x, v0.y, v0.z, v0.w, v1.x, v1.y, v1.z, v1.w};
                    V8 rh, rl;
#pragma unroll
                    for (int j = 0; j < 4; ++j){
                        uint u0 = __float_as_uint(vv[2*j]);
                        uint u1 = __float_as_uint(vv[2*j+1]);
                        rh.u[j] = (u0 >> 16) | (u1 & 0xFFFF0000u);      // trunc hi
                        float r0 = vv[2*j]   - __uint_as_float(u0 & 0xFFFF0000u);
                        float r1 = vv[2*j+1] - __uint_as_float(u1 & 0xFFFF0000u);
                        rl.u[j] = (__float_as_uint(r0) >> 16) |
                                  (__float_as_uint(r1) & 0xFFFF0000u);  // trunc lo
                    }
                    // transpose-store rh into sRT[c][s]; qt0 covers k<8, qt1 k>=8
                    if (qt == (k >> 3)){
#pragma unroll
                        for (int j = 0; j < 8; ++j)
                            sRT[(c0 + j) * LSTR + st * 32 + l31] =
                                (uint16_t)(rh.u[j >> 1] >> ((j & 1) * 16));
                    }
                    const uint4* qp = qf + ((size_t)((qt * 16 + k) * 64 + lane)) * 2;
                    V8 qh, ql;
                    uint4 t0 = qp[0], t1 = qp[1];
                    qh.u[0]=t0.x; qh.u[1]=t0.y; qh.u[2]=t0.z; qh.u[3]=t0.w;
                    ql.u[0]=t1.x; ql.u[1]=t1.y; ql.u[2]=t1.z; ql.u[3]=t1.w;
                    if (k & 1){
                        a1b = MFMA_BF16(rh.v, qh.v, a1b, 0, 0, 0);
                        a1b = MFMA_BF16(rh.v, ql.v, a1b, 0, 0, 0);
                        a1b = MFMA_BF16(rl.v, qh.v, a1b, 0, 0, 0);
                    } else {
                        a1a = MFMA_BF16(rh.v, qh.v, a1a, 0, 0, 0);
                        a1a = MFMA_BF16(rh.v, ql.v, a1a, 0, 0, 0);
                        a1a = MFMA_BF16(rl.v, qh.v, a1a, 0, 0, 0);
                    }
                }
            } else {
                const float* qrow = Qg + qq * CC;
                const bool qok = qq < NQ;
#pragma unroll
                for (int k = 0; k < 16; ++k){
                    int c0 = k * 16 + lh * 8;
                    float4 v0 = *(const float4*)(ar + c0);
                    float4 v1 = *(const float4*)(ar + c0 + 4);
                    float vv[8] = {v0.x, v0.y, v0.z, v0.w, v1.x, v1.y, v1.z, v1.w};
                    V8 rh, rl, qh, ql;
#pragma unroll
                    for (int j = 0; j < 4; ++j){
                        uint u0 = __float_as_uint(vv[2*j]);
                        uint u1 = __float_as_uint(vv[2*j+1]);
                        rh.u[j] = (u0 >> 16) | (u1 & 0xFFFF0000u);
                        float r0 = vv[2*j]   - __uint_as_float(u0 & 0xFFFF0000u);
                        float r1 = vv[2*j+1] - __uint_as_float(u1 & 0xFFFF0000u);
                        rl.u[j] = (__float_as_uint(r0) >> 16) |
                                  (__float_as_uint(r1) & 0xFFFF0000u);
                        float qa = qok ? qrow[c0 + 2*j]     : 0.f;
                        float qb = qok ? qrow[c0 + 2*j + 1] : 0.f;
                        uint16_t h0 = f2bf_rne(qa), h1 = f2bf_rne(qb);
                        uint16_t g0 = f2bf_rne(qa - bf2f(h0));
                        uint16_t g1 = f2bf_rne(qb - bf2f(h1));
                        qh.u[j] = (uint)h0 | ((uint)h1 << 16);
                        ql.u[j] = (uint)g0 | ((uint)g1 << 16);
                    }
                    if (qt == (k >> 3)){
#pragma unroll
                        for (int j = 0; j < 8; ++j)
                            sRT[(c0 + j) * LSTR + st * 32 + l31] =
                                (uint16_t)(rh.u[j >> 1] >> ((j & 1) * 16));
                    }
                    if (k & 1){
                        a1b = MFMA_BF16(rh.v, qh.v, a1b, 0, 0, 0);
                        a1b = MFMA_BF16(rh.v, ql.v, a1b, 0, 0, 0);
                        a1b = MFMA_BF16(rl.v, qh.v, a1b, 0, 0, 0);
                    } else {
                        a1a = MFMA_BF16(rh.v, qh.v, a1a, 0, 0, 0);
                        a1a = MFMA_BF16(rh.v, ql.v, a1a, 0, 0, 0);
                        a1a = MFMA_BF16(rl.v, qh.v, a1a, 0, 0, 0);
                    }
                }
            }
        }

        // ---- exp(score - 40) -> bf16 P[q][s], accumulate l ----
        // C/D map (32x32): col=q=lane&31, row=s=(reg&3)+8*(reg>>2)+4*lh
#pragma unroll
        for (int g2 = 0; g2 < 4; ++g2){
            uint16_t e[4];
#pragma unroll
            for (int r2 = 0; r2 < 4; ++r2){
                float sc = a1a[g2 * 4 + r2] + a1b[g2 * 4 + r2];
                float pv = exp2f(sc * 1.4426950408889634f - 57.70780163555852f);
                e[r2] = f2bf_rne(pv);
                lp += bf2f(e[r2]);                 // l consistent with bf16 P
            }
            int sl = st * 32 + g2 * 8 + lh * 4;
            *(uint2*)&sP[qq * LSTR + sl] =
                make_uint2((uint)e[0] | ((uint)e[1] << 16),
                           (uint)e[2] | ((uint)e[3] << 16));
        }
        __syncthreads();

        // ---- GEMM2: O[q][c] += P[q][s] * r[s][c] ----
#pragma unroll
        for (int k = 0; k < 4; ++k){
            int so = k * 16 + lh * 8;
            short8 A0 = *(const short8*)&sP [(mp * 64      + l31) * LSTR + so];
            short8 A1 = *(const short8*)&sP [(mp * 64 + 32 + l31) * LSTR + so];
            short8 B0 = *(const short8*)&sRT[(cq * 64      + l31) * LSTR + so];
            short8 B1 = *(const short8*)&sRT[(cq * 64 + 32 + l31) * LSTR + so];
            acc00 = MFMA_BF16(A0, B0, acc00, 0, 0, 0);
            acc01 = MFMA_BF16(A0, B1, acc01, 0, 0, 0);
            acc10 = MFMA_BF16(A1, B0, acc10, 0, 0, 0);
            acc11 = MFMA_BF16(A1, B1, acc11, 0, 0, 0);
        }
        __syncthreads();
    }

    // ---- reduce l within wg ----
    atomicAdd(&sL[qq], lp);
    __syncthreads();

    const int c0 = cq * 64 + l31;
    if (split == 1){
        float* ob = out + (size_t)bn * PO_PER;
#pragma unroll
        for (int r = 0; r < 16; ++r){
            int row = (r & 3) + 8 * (r >> 2) + 4 * lh;
            int q0 = mp * 64 + row;
            int q1 = q0 + 32;
            if (q0 < NQ){
                float inv = 1.0f / sL[q0];
                ob[q0 * CC + c0]      = acc00[r] * inv;
                ob[q0 * CC + c0 + 32] = acc01[r] * inv;
            }
            if (q1 < NQ){
                float inv = 1.0f / sL[q1];
                ob[q1 * CC + c0]      = acc10[r] * inv;
                ob[q1 * CC + c0 + 32] = acc11[r] * inv;
            }
        }
    } else {
        float* ob = po + ((size_t)bn * split + seg) * PO_PER;
#pragma unroll
        for (int r = 0; r < 16; ++r){
            int row = (r & 3) + 8 * (r >> 2) + 4 * lh;
            int q0 = mp * 64 + row;
            int q1 = q0 + 32;
            if (q0 < NQ){
                ob[q0 * CC + c0]      = acc00[r];
                ob[q0 * CC + c0 + 32] = acc01[r];
            }
            if (q1 < NQ){
                ob[q1 * CC + c0]      = acc10[r];
                ob[q1 * CC + c0 + 32] = acc11[r];
            }
        }
        if (tid < 128) pl[((size_t)bn * split + seg) * 128 + tid] = sL[tid];
    }
}

// ---------------------------------------------------------------------------
// Phase B: sum partials across segments, normalize, write out.
// grid = 196, 512 threads.
// ---------------------------------------------------------------------------
__global__ __launch_bounds__(512) void reduce_kernel(
        const float* __restrict__ po, const float* __restrict__ pl,
        float* __restrict__ out, int split)
{
    __shared__ float sInv[128];
    const int bn = blockIdx.x, tid = threadIdx.x;
    if (tid < 128){
        float s = 0.f;
        for (int g = 0; g < split; ++g)
            s += pl[((size_t)bn * split + g) * 128 + tid];
        sInv[tid] = 1.0f / s;
    }
    __syncthreads();
    const float* base = po + (size_t)bn * split * PO_PER;
    float* ob = out + (size_t)bn * PO_PER;
#pragma unroll 2
    for (int i = 0; i < PO_PER / 512; ++i){      // 50 iters, coalesced
        int idx = i * 512 + tid;
        float s = 0.f;
        for (int g = 0; g < split; ++g) s += base[g * PO_PER + idx];
        ob[idx] = s * sInv[idx >> 8];
    }
}

extern "C" void kernel_launch(void* const* d_in, const int* in_sizes, int n_in,
                              void* d_out, int out_size, void* d_ws, size_t ws_size,
                              hipStream_t stream){
    const float* img = (const float*)d_in[0];
    const float* Qg  = (const float*)d_in[1];
    float* out = (float*)d_out;

    uint4* qf = nullptr;
    size_t off = 0;
    if (ws_size >= QF_BYTES){
        qf = (uint4*)d_ws;
        off = QF_BYTES;
        qfrag_kernel<<<8, 512, 0, stream>>>(Qg, qf);
    }

    int split = 1;
    const size_t per_seg = (size_t)196 * (PO_PER + 128) * sizeof(float);
    if (ws_size >= off + 4 * per_seg)      split = 4;
    else if (ws_size >= off + 2 * per_seg) split = 2;

    float *po = nullptr, *pl = nullptr;
    if (split > 1){
        po = (float*)((char*)d_ws + off);
        pl = po + (size_t)196 * split * PO_PER;
    }

    attn_kernel<<<196 * split, 512, 0, stream>>>(img, Qg, qf, out, po, pl, split);
    if (split > 1)
        reduce_kernel<<<196, 512, 0, stream>>>(po, pl, out, split);
}

// Round 4
// 358.035 us; speedup vs baseline: 1.7479x; 1.7479x over previous
//
#include <hip/hip_runtime.h>
#include <stdint.h>

typedef short short8 __attribute__((ext_vector_type(8)));
typedef __fp16 fp16x8 __attribute__((ext_vector_type(8)));
typedef float f32x16 __attribute__((ext_vector_type(16)));
typedef unsigned int uint;

#define NREG 49
#define NQ   100
#define CC   256
#define OUT_POS_OFF 5017600        // 4*49*100*256
#define PO_PER (NQ*CC)             // 25600 floats per (bn,seg) partial
#define QF_BYTES 65536             // 64 frags * 64 lanes * 16 B (fp16)
#define MFMA_BF16 __builtin_amdgcn_mfma_f32_32x32x16_bf16
#define MFMA_F16  __builtin_amdgcn_mfma_f32_32x32x16_f16

union U4H8 { uint4 u; fp16x8 h; short8 s; };

__device__ __forceinline__ uint pkrtz(float a, float b){
    auto v = __builtin_amdgcn_cvt_pkrtz(a, b);   // __fp16 x2, RTZ
    return __builtin_bit_cast(uint, v);
}
__device__ __forceinline__ uint16_t f2bf_rne(float x){
    uint u = __float_as_uint(x);
    u += 0x7fffu + ((u >> 16) & 1u);
    return (uint16_t)(u >> 16);
}
__device__ __forceinline__ float bf2f(uint16_t b){
    return __uint_as_float(((uint)b) << 16);
}

// ---------------------------------------------------------------------------
// Kernel 0: Q fragments in fp16, exact 32x32x16 B-operand order.
// frag = qt*16 + k; lane holds Q[q = qt*32 + (lane&31)][c = k*16 + (lane>>5)*8 + j]
// ---------------------------------------------------------------------------
__global__ __launch_bounds__(512) void qfrag_kernel(const float* __restrict__ Qg,
                                                    uint4* __restrict__ qf){
    int gid  = blockIdx.x * 512 + threadIdx.x;   // 0..4095
    int lane = gid & 63;
    int frag = gid >> 6;                         // 0..63
    int k    = frag & 15;
    int qt   = frag >> 4;
    int q    = qt * 32 + (lane & 31);
    int c0   = k * 16 + (lane >> 5) * 8;
    float v[8];
#pragma unroll
    for (int j = 0; j < 8; ++j) v[j] = (q < NQ) ? Qg[q * CC + c0 + j] : 0.f;
    qf[gid] = make_uint4(pkrtz(v[0], v[1]), pkrtz(v[2], v[3]),
                         pkrtz(v[4], v[5]), pkrtz(v[6], v[7]));
}

// ---------------------------------------------------------------------------
// Phase A: fused attention over an s-segment of one (b, region).
// 512 threads, 1 wg/CU (64 KB LDS). grid = 196*split.
// LDS layout (byte offsets):
//   [0, 32768)      sRT: bf16 GEMM2-B frag-order, XOR-swizzled by c-group
//   [32768, 65536)  union region:
//       phase stage/G1: sAf fp16 GEMM1-A frag-order (32 KB)
//       phase exp/G2:   sP  bf16 GEMM2-A frag-order (low 16 KB)
//       post-loop:      sL  float[128] softmax denominators
// ---------------------------------------------------------------------------
__global__ __launch_bounds__(512, 2) void attn_kernel(
        const float* __restrict__ img, const uint4* __restrict__ qf,
        float* __restrict__ out, float* __restrict__ po,
        float* __restrict__ pl, int split)
{
    __shared__ __align__(16) unsigned char smem[65536];
    unsigned char* sRT = smem;
    unsigned char* sU  = smem + 32768;

    const int tid = threadIdx.x;
    const int seg = blockIdx.x % split;
    const int bn  = blockIdx.x / split;    // 0..195
    const int rr  = bn % NREG;
    const int bb  = bn / NREG;
    const int gh  = rr / 7, gw = rr % 7;

    if (bn == 0 && seg == 0 && tid < NREG){    // positions output
        out[OUT_POS_OFF + 2 * tid]     = (float)((tid / 7) / 7.0);
        out[OUT_POS_OFF + 2 * tid + 1] = (float)((tid % 7) / 7.0);
    }

    const int lane = tid & 63, w = tid >> 6;
    const int l31  = lane & 31;
    const int st = w & 1, qt = w >> 1;     // GEMM1 roles
    const int mp = w & 1, cq = w >> 1;     // GEMM2 roles

    // staging roles: thread covers pixel sloc, columns [ct*32, ct*32+32)
    const int sloc = tid >> 3;             // 0..63
    const int ct   = tid & 7;
    const int stw  = sloc >> 5;            // sAf frag half
    const int s31  = sloc & 31;
    const int ksw  = sloc >> 4;            // sRT kstep
    const int lhw  = (sloc >> 3) & 1;
    const int jw   = sloc & 7;
    // sRT write: element i (c = ct*32+i) at rtwbase + ((i^ct)<<4)
    const int rtwbase = ((ksw * 8 + ct) * 64 + lhw * 32) * 16 + jw * 2;
    // sAf write for run r (i = 8r..8r+7): afwbase + (r>>1)*1024 + (r&1)*512
    const int afwbase = (stw * 16 + ct * 2) * 1024 + s31 * 16;

    const float* rbase = img + ((size_t)(bb * 224 + gh * 32) * 224 + gw * 32) * CC;

    // Q fragments in registers (fp16): 16 x 16B
    uint4 qr[16];
#pragma unroll
    for (int k = 0; k < 16; ++k) qr[k] = qf[(qt * 16 + k) * 64 + lane];

    f32x16 acc00, acc01, acc10, acc11;
#pragma unroll
    for (int i = 0; i < 16; ++i){ acc00[i]=0.f; acc01[i]=0.f; acc10[i]=0.f; acc11[i]=0.f; }
    float lp = 0.f;
    const int qq = qt * 32 + l31;

    const int nch = 16 / split;
    const int ch0 = seg * nch, ch1 = ch0 + nch;

    float4 rb[8], rb2[8];
    {   // preload first chunk
        int p = ch0 * 64 + sloc;
        const float* gp = rbase + ((p >> 5) * 224 + (p & 31)) * CC + ct * 32;
#pragma unroll
        for (int j = 0; j < 8; ++j) rb[j] = *(const float4*)(gp + j * 4);
    }

    for (int ch = ch0; ch < ch1; ++ch){
        // ---- stage: rb -> sAf (fp16 frag-order) + sRT (bf16, swizzled) ----
#pragma unroll
        for (int r = 0; r < 4; ++r){
            uint4 o = make_uint4(pkrtz(rb[2*r].x,   rb[2*r].y),
                                 pkrtz(rb[2*r].z,   rb[2*r].w),
                                 pkrtz(rb[2*r+1].x, rb[2*r+1].y),
                                 pkrtz(rb[2*r+1].z, rb[2*r+1].w));
            *(uint4*)(sU + afwbase + ((r >> 1) * 1024) + ((r & 1) * 512)) = o;
        }
#pragma unroll
        for (int i = 0; i < 32; ++i){
            const float* fp = (const float*)rb;
            uint u = __float_as_uint(fp[i]);
            *(uint16_t*)(sRT + rtwbase + ((i ^ ct) << 4)) = (uint16_t)(u >> 16);
        }

        // ---- prefetch next chunk ----
        if (ch + 1 < ch1){
            int p = (ch + 1) * 64 + sloc;
            const float* gp = rbase + ((p >> 5) * 224 + (p & 31)) * CC + ct * 32;
#pragma unroll
            for (int j = 0; j < 8; ++j) rb2[j] = *(const float4*)(gp + j * 4);
        }
        __syncthreads();   // B1: staged data visible

        // ---- GEMM1 (fp16): scoresT[s][q], wave (st, qt) ----
        f32x16 a1;
#pragma unroll
        for (int i = 0; i < 16; ++i) a1[i] = 0.f;
#pragma unroll
        for (int k = 0; k < 16; ++k){
            U4H8 af; af.u = *(const uint4*)(sU + ((st * 16 + k) * 64 + lane) * 16);
            U4H8 bq; bq.u = qr[k];
            a1 = MFMA_F16(af.h, bq.h, a1, 0, 0, 0);
        }
        __syncthreads();   // B2: GEMM1 reads of sAf done before sP overwrites

        // ---- exp(score-40) -> bf16 sP (GEMM2-A frag-order), accumulate l ----
        // C/D map: col=q=lane&31, row=s_local=(reg&3)+8*(reg>>2)+4*(lane>>5)
#pragma unroll
        for (int g2 = 0; g2 < 4; ++g2){
            uint16_t e[4];
#pragma unroll
            for (int r2 = 0; r2 < 4; ++r2){
                float sc = a1[g2 * 4 + r2];
                float pv = exp2f(sc * 1.4426950408889634f - 57.70780163555852f);
                e[r2] = f2bf_rne(pv);
                lp += bf2f(e[r2]);
            }
            int kst = st * 2 + (g2 >> 1);
            int boff = ((kst * 4 + qt) * 64 + (g2 & 1) * 32 + l31) * 16 + (lane >> 5) * 8;
            *(uint2*)(sU + boff) = make_uint2((uint)e[0] | ((uint)e[1] << 16),
                                              (uint)e[2] | ((uint)e[3] << 16));
        }
        __syncthreads();   // B3: sP visible

        // ---- GEMM2 (bf16): O[q][c] += P * R, wave (mp, cq) ----
#pragma unroll
        for (int ks = 0; ks < 4; ++ks){
            U4H8 A0, A1, B0, B1;
            A0.u = *(const uint4*)(sU  + ((ks * 4 + mp * 2    ) * 64 + lane) * 16);
            A1.u = *(const uint4*)(sU  + ((ks * 4 + mp * 2 + 1) * 64 + lane) * 16);
            B0.u = *(const uint4*)(sRT + ((ks * 8 + cq * 2    ) * 64 + (lane ^ (cq * 2    ))) * 16);
            B1.u = *(const uint4*)(sRT + ((ks * 8 + cq * 2 + 1) * 64 + (lane ^ (cq * 2 + 1))) * 16);
            acc00 = MFMA_BF16(A0.s, B0.s, acc00, 0, 0, 0);
            acc01 = MFMA_BF16(A0.s, B1.s, acc01, 0, 0, 0);
            acc10 = MFMA_BF16(A1.s, B0.s, acc10, 0, 0, 0);
            acc11 = MFMA_BF16(A1.s, B1.s, acc11, 0, 0, 0);
        }
        __syncthreads();   // B4: GEMM2 reads done before next stage writes

        if (ch + 1 < ch1){
#pragma unroll
            for (int j = 0; j < 8; ++j) rb[j] = rb2[j];
        }
    }

    // ---- softmax denominators via LDS (aliased region, re-initialized) ----
    float* sL = (float*)sU;
    if (tid < 128) sL[tid] = 0.f;
    __syncthreads();
    atomicAdd(&sL[qq], lp);
    __syncthreads();

    const int c0 = cq * 64 + l31;
    if (split == 1){
        float* ob = out + (size_t)bn * PO_PER;
#pragma unroll
        for (int r = 0; r < 16; ++r){
            int row = (r & 3) + 8 * (r >> 2) + 4 * (lane >> 5);
            int q0 = mp * 64 + row, q1 = q0 + 32;
            if (q0 < NQ){
                float inv = 1.0f / sL[q0];
                ob[q0 * CC + c0]      = acc00[r] * inv;
                ob[q0 * CC + c0 + 32] = acc01[r] * inv;
            }
            if (q1 < NQ){
                float inv = 1.0f / sL[q1];
                ob[q1 * CC + c0]      = acc10[r] * inv;
                ob[q1 * CC + c0 + 32] = acc11[r] * inv;
            }
        }
    } else {
        float* ob = po + ((size_t)bn * split + seg) * PO_PER;
#pragma unroll
        for (int r = 0; r < 16; ++r){
            int row = (r & 3) + 8 * (r >> 2) + 4 * (lane >> 5);
            int q0 = mp * 64 + row, q1 = q0 + 32;
            if (q0 < NQ){
                ob[q0 * CC + c0]      = acc00[r];
                ob[q0 * CC + c0 + 32] = acc01[r];
            }
            if (q1 < NQ){
                ob[q1 * CC + c0]      = acc10[r];
                ob[q1 * CC + c0 + 32] = acc11[r];
            }
        }
        if (tid < 128) pl[((size_t)bn * split + seg) * 128 + tid] = sL[tid];
    }
}

// ---------------------------------------------------------------------------
// Phase B: sum partials across segments, normalize, write out.
// grid = 392 (2 wgs per bn), 512 threads.
// ---------------------------------------------------------------------------
__global__ __launch_bounds__(512) void reduce_kernel(
        const float* __restrict__ po, const float* __restrict__ pl,
        float* __restrict__ out, int split)
{
    __shared__ float sInv[64];
    const int bn = blockIdx.x >> 1, hf = blockIdx.x & 1, tid = threadIdx.x;
    if (tid < 50){
        int q = hf * 50 + tid;
        float s = 0.f;
        for (int g = 0; g < split; ++g)
            s += pl[((size_t)bn * split + g) * 128 + q];
        sInv[tid] = 1.0f / s;
    }
    __syncthreads();
    const float* base = po + (size_t)bn * split * PO_PER;
    float* ob = out + (size_t)bn * PO_PER;
#pragma unroll 1
    for (int i = 0; i < 25; ++i){
        int idx = hf * 12800 + i * 512 + tid;
        float s = 0.f;
        for (int g = 0; g < split; ++g) s += base[g * PO_PER + idx];
        ob[idx] = s * sInv[(idx >> 8) - hf * 50];
    }
}

extern "C" void kernel_launch(void* const* d_in, const int* in_sizes, int n_in,
                              void* d_out, int out_size, void* d_ws, size_t ws_size,
                              hipStream_t stream){
    const float* img = (const float*)d_in[0];
    const float* Qg  = (const float*)d_in[1];
    float* out = (float*)d_out;

    uint4* qf = (uint4*)d_ws;
    qfrag_kernel<<<8, 512, 0, stream>>>(Qg, qf);

    int split = 1;
    const size_t per_seg = (size_t)196 * (PO_PER + 128) * sizeof(float);
    if (ws_size >= QF_BYTES + 4 * per_seg) split = 4;

    float *po = nullptr, *pl = nullptr;
    if (split > 1){
        po = (float*)((char*)d_ws + QF_BYTES);
        pl = po + (size_t)196 * split * PO_PER;
    }

    attn_kernel<<<196 * split, 512, 0, stream>>>(img, qf, out, po, pl, split);
    if (split > 1)
        reduce_kernel<<<392, 512, 0, stream>>>(po, pl, out, split);
}